// Round 21
// baseline (235.501 us; speedup 1.0000x reference)
//
#include <hip/hip_runtime.h>
#include <hip/hip_bf16.h>
#include <stdint.h>

#define DM 1024
#define DKH 64
#define NH 16
#define NB 4
#define SEQ 2048

typedef __attribute__((ext_vector_type(8))) short bf16x8;
typedef __attribute__((ext_vector_type(4))) short bf16x4;
typedef __attribute__((ext_vector_type(8))) unsigned short ushort8;
typedef __attribute__((ext_vector_type(4))) float f32x4;

union S8 { bf16x8 w; bf16x4 h[2]; };

__device__ inline unsigned short f2bf(float f) {
  union { float f; unsigned u; } c; c.f = f;
  unsigned u = c.u;
  u += 0x7fff + ((u >> 16) & 1);   // round-to-nearest-even
  return (unsigned short)(u >> 16);
}

// forced (un-sinkable) global loads with literal byte offsets
#define GLOAD16(dst, ptr, OFF)                                              \
  asm volatile("global_load_dwordx4 %0, %1, off offset:" #OFF               \
               : "=v"(dst) : "v"(ptr))

#define WAITV(N)                                            \
  do {                                                      \
    asm volatile("s_waitcnt vmcnt(" #N ")" ::: "memory");   \
    __builtin_amdgcn_sched_barrier(0);                      \
  } while (0)

// async global->LDS, 16B per lane; lds dest = wave-uniform base + lane*16
__device__ inline void glds16(const unsigned short* g, unsigned short* l) {
  __builtin_amdgcn_global_load_lds(
      (const __attribute__((address_space(1))) unsigned int*)g,
      (__attribute__((address_space(3))) unsigned int*)l, 16, 0, 0);
}

// PV matrix op: D/C = acc (4 VGPR), A = V-frag (4 bf16), B = P-frag (4 bf16)
__device__ inline void mfma16x16x16(f32x4& acc, bf16x4 a, bf16x4 b) {
  asm("v_mfma_f32_16x16x16_bf16 %0, %1, %2, %0" : "+v"(acc) : "v"(a), "v"(b));
}

// ---------- fp32 -> bf16 elementwise cast (8 elems/thread) ----------
__global__ __launch_bounds__(256) void acast(const float* __restrict__ A,
                                             unsigned short* __restrict__ O) {
  size_t i = ((size_t)blockIdx.x * 256 + threadIdx.x) * 8;
  const float* p = A + i;
  float4 x = *reinterpret_cast<const float4*>(p);
  float4 y = *reinterpret_cast<const float4*>(p + 4);
  ushort8 v;
  v[0] = f2bf(x.x); v[1] = f2bf(x.y); v[2] = f2bf(x.z); v[3] = f2bf(x.w);
  v[4] = f2bf(y.x); v[5] = f2bf(y.y); v[6] = f2bf(y.z); v[7] = f2bf(y.w);
  *reinterpret_cast<ushort8*>(O + i) = v;
}

// ---------- 4 weight transposes in one dispatch: Wt[n][k] = bf16(W[k][n]) ------
__global__ __launch_bounds__(256) void wcast_all(const float* __restrict__ W0,
                                                 const float* __restrict__ W1,
                                                 const float* __restrict__ W2,
                                                 const float* __restrict__ W3,
                                                 unsigned short* __restrict__ Wt0,
                                                 unsigned short* __restrict__ Wt1,
                                                 unsigned short* __restrict__ Wt2,
                                                 unsigned short* __restrict__ Wt3) {
  __shared__ float tile[32][33];
  int z = blockIdx.z;
  const float* W = z == 0 ? W0 : z == 1 ? W1 : z == 2 ? W2 : W3;
  unsigned short* Wt = z == 0 ? Wt0 : z == 1 ? Wt1 : z == 2 ? Wt2 : Wt3;
  int bk = blockIdx.x * 32, bn = blockIdx.y * 32;
  int tx = threadIdx.x & 31, ty = threadIdx.x >> 5;  // ty 0..7
#pragma unroll
  for (int i = 0; i < 4; ++i)
    tile[ty + 8 * i][tx] = W[(size_t)(bk + ty + 8 * i) * DM + bn + tx];
  __syncthreads();
#pragma unroll
  for (int i = 0; i < 4; ++i)
    Wt[(size_t)(bn + ty + 8 * i) * DM + bk + tx] = f2bf(tile[tx][ty + 8 * i]);
}

// ---------- bf16 GEMM: double-buffered LDS + counted vmcnt (T4) ----------
// M=8192, N=1024, K=1024, 128x128 tile, BK=32, 512 blocks.
// EPI: 0 = Q [B,H,S,64] bf16 (scaled); 1 = K' attn-native; 2 = V'' attn-native
//      packed; 3 = fp32 out row-major.
template <int EPI>
__global__ __launch_bounds__(256) void gemm_bf16(const unsigned short* __restrict__ A,
                                                 const unsigned short* __restrict__ Bt,
                                                 const float* __restrict__ bias,
                                                 void* __restrict__ Cv, float scale) {
  __shared__ __align__(16) unsigned short As[2][128][32];
  __shared__ __align__(16) unsigned short Bs[2][128][32];
  const int K = DM;
  int t = threadIdx.x;
  int wave = t >> 6, lane = t & 63;
  int wr = wave >> 1, wc = wave & 1;
  int l15 = lane & 15, g = lane >> 4;
  // XCD-locality swizzle (bijective on [0,512))
  int bid = blockIdx.x;
  int xcd = bid & 7, ii = bid >> 3;
  int tn = ii >> 3;                    // 0..7
  int tm = ((ii & 7) << 3) | xcd;      // 0..63
  int rowBase = tm * 128, colBase = tn * 128;

  f32x4 acc[4][4];
#pragma unroll
  for (int mi = 0; mi < 4; ++mi)
#pragma unroll
    for (int ni = 0; ni < 4; ++ni) acc[mi][ni] = (f32x4){0.f, 0.f, 0.f, 0.f};

  const unsigned short* sa0 =
      A + (size_t)(rowBase + wave * 16 + (lane >> 2)) * K + (lane & 3) * 8;
  const unsigned short* sa1 = sa0 + (size_t)64 * K;
  const unsigned short* sb0 =
      Bt + (size_t)(colBase + wave * 16 + (lane >> 2)) * K + (lane & 3) * 8;
  const unsigned short* sb1 = sb0 + (size_t)64 * K;

#define STAGE(BUF)                                   \
  do {                                               \
    glds16(sa0, &As[BUF][wave * 16][0]);             \
    glds16(sa1, &As[BUF][64 + wave * 16][0]);        \
    glds16(sb0, &Bs[BUF][wave * 16][0]);             \
    glds16(sb1, &Bs[BUF][64 + wave * 16][0]);        \
    sa0 += 32; sa1 += 32; sb0 += 32; sb1 += 32;      \
  } while (0)

#define COMPUTE(BUF)                                                            \
  do {                                                                          \
    bf16x8 af[4], bfr[4];                                                       \
    _Pragma("unroll")                                                           \
    for (int mi = 0; mi < 4; ++mi)                                              \
      af[mi] = *reinterpret_cast<const bf16x8*>(                                \
          &As[BUF][wr * 64 + mi * 16 + l15][g * 8]);                            \
    _Pragma("unroll")                                                           \
    for (int ni = 0; ni < 4; ++ni)                                              \
      bfr[ni] = *reinterpret_cast<const bf16x8*>(                               \
          &Bs[BUF][wc * 64 + ni * 16 + l15][g * 8]);                            \
    _Pragma("unroll")                                                           \
    for (int mi = 0; mi < 4; ++mi)                                              \
      _Pragma("unroll")                                                         \
      for (int ni = 0; ni < 4; ++ni)                                            \
        acc[mi][ni] = __builtin_amdgcn_mfma_f32_16x16x32_bf16(af[mi], bfr[ni],  \
                                                              acc[mi][ni], 0, 0, 0); \
  } while (0)

  STAGE(0);  // tile 0 in flight (4 DMAs)
#pragma unroll 1
  for (int it = 0; it < 16; ++it) {   // each iteration: tiles 2it, 2it+1
    __syncthreads();                  // all waves done reading buf1 (prev iter)
    STAGE(1);                         // tile 2it+1 -> buf1
    WAITV(4);                         // my buf0 DMAs (tile 2it) complete
    __syncthreads();                  // everyone's buf0 complete
    COMPUTE(0);
    __syncthreads();                  // all waves done reading buf0
    if (it < 15) {
      STAGE(0);                       // tile 2it+2 -> buf0
      WAITV(4);                       // buf1 (tile 2it+1) complete
    } else {
      WAITV(0);                       // final drain
    }
    __syncthreads();
    COMPUTE(1);
  }
#undef STAGE
#undef COMPUTE

#pragma unroll
  for (int ni = 0; ni < 4; ++ni) {
    int col = colBase + wc * 64 + ni * 16 + l15;
    float bvv = bias[col];
#pragma unroll
    for (int mi = 0; mi < 4; ++mi) {
#pragma unroll
      for (int r = 0; r < 4; ++r) {
        int row = rowBase + wr * 64 + mi * 16 + g * 4 + r;
        float val = (acc[mi][ni][r] + bvv) * scale;
        if (EPI == 3) {
          ((float*)Cv)[(size_t)row * DM + col] = val;
        } else {
          int b_ = row >> 11, s_ = row & 2047;
          int h_ = col >> 6, d_ = col & 63;
          size_t hb = (size_t)(b_ * NH + h_) * (SEQ * DKH);
          size_t idx;
          if (EPI == 0) {
            idx = hb + (size_t)s_ * DKH + d_;
          } else if (EPI == 1) {
            idx = hb + (size_t)(s_ >> 4) * 1024 + (d_ >> 5) * 512 +
                  ((d_ >> 3) & 3) * 128 + (s_ & 15) * 8 + (d_ & 7);
          } else {
            // V'' packed: lane(g,l15) reads 16B = {tt=0 j0..3, tt=1 j0..3}
            idx = hb + (size_t)(s_ >> 5) * 2048 + (d_ >> 4) * 512 +
                  ((s_ >> 2) & 3) * 128 + (d_ & 15) * 8 + ((s_ >> 4) & 1) * 4 +
                  (s_ & 3);
          }
          ((unsigned short*)Cv)[idx] = f2bf(val);
        }
      }
    }
  }
}

// ---------- flash attention: zero-LDS, fixed-offset softmax, 1-wave blocks ------
// Body identical to the twice-passing r13/r18 kernel; each wave is fully
// independent, so each becomes its own 64-thread block (grid 4096). A CU can
// then pack ~16 independent blocks -> the per-wave serial chunk chain is
// covered by cross-wave TLP (4-wave blocks were limited to ~6 waves/CU
// resident per the occupancy counter).
__global__ __launch_bounds__(64) void attn_fwd(const unsigned short* __restrict__ Qb,
                                               const unsigned short* __restrict__ Kp_,
                                               const unsigned short* __restrict__ Vp_,
                                               unsigned short* __restrict__ AO) {
  int lane = threadIdx.x;
  int l15 = lane & 15, g = lane >> 4;
  int bid = blockIdx.x;                 // 0..4095
  int xcd = bid & 7, j = bid >> 3;      // j 0..511
  int bh = (xcd << 3) | (j >> 6);       // 0..63 (all 64 tiles of a bh on one XCD)
  int tile = j & 63;                    // 0..63
  const size_t baseH = (size_t)bh * SEQ * DKH;
  int q0 = tile * 32;

  bf16x8 aQ[2][2];
#pragma unroll
  for (int qf = 0; qf < 2; ++qf)
#pragma unroll
    for (int dh = 0; dh < 2; ++dh)
      aQ[qf][dh] = *reinterpret_cast<const bf16x8*>(
          Qb + baseH + (size_t)(q0 + qf * 16 + l15) * DKH + dh * 32 + g * 8);

  float lsum[2] = {0.f, 0.f};
  f32x4 accO[2][4];  // accO[qf][dt][r] = O[q=l15][d=dt*16+g*4+r]
#pragma unroll
  for (int qf = 0; qf < 2; ++qf)
#pragma unroll
    for (int dt = 0; dt < 4; ++dt) accO[qf][dt] = (f32x4){0.f, 0.f, 0.f, 0.f};

  const unsigned short* kp = Kp_ + baseH + g * 128 + l15 * 8;
  const unsigned short* vp = Vp_ + baseH + (size_t)lane * 8;  // lane*16B

  bf16x8 k0[2][2], k1[2][2], k2[2][2];
  S8 v0[4], v1[4], v2[4];
  bf16x4 pf[2][2];

#define ISSUE_K(buf)                                  \
  do {                                                \
    GLOAD16(buf[0][0], kp, 0);                        \
    GLOAD16(buf[0][1], kp, 1024);                     \
    GLOAD16(buf[1][0], kp, 2048);                     \
    GLOAD16(buf[1][1], kp, 3072);                     \
    kp += 2048;                                       \
  } while (0)
#define ISSUE_V(buf)                                  \
  do {                                                \
    GLOAD16(buf[0].w, vp, 0);                         \
    GLOAD16(buf[1].w, vp, 1024);                      \
    GLOAD16(buf[2].w, vp, 2048);                      \
    GLOAD16(buf[3].w, vp, 3072);                      \
    vp += 2048;                                       \
  } while (0)

  const f32x4 ZOFF = (f32x4){-16.f, -16.f, -16.f, -16.f};

  auto qksm = [&](const bf16x8 (&kf)[2][2]) {
    f32x4 sc[2][2];
    __builtin_amdgcn_s_setprio(1);
#pragma unroll
    for (int qf = 0; qf < 2; ++qf)
#pragma unroll
      for (int tt = 0; tt < 2; ++tt) {
        f32x4 z = ZOFF;  // C-init = -16: folds the softmax offset for free
#pragma unroll
        for (int dh = 0; dh < 2; ++dh)
          z = __builtin_amdgcn_mfma_f32_16x16x32_bf16(kf[tt][dh], aQ[qf][dh], z, 0, 0, 0);
        sc[qf][tt] = z;
      }
    __builtin_amdgcn_s_setprio(0);
#pragma unroll
    for (int qf = 0; qf < 2; ++qf) {
      float pv[8];
#pragma unroll
      for (int tt = 0; tt < 2; ++tt)
#pragma unroll
        for (int r = 0; r < 4; ++r)
          pv[tt * 4 + r] = __builtin_amdgcn_exp2f(sc[qf][tt][r]);
      lsum[qf] +=
          ((pv[0] + pv[1]) + (pv[2] + pv[3])) + ((pv[4] + pv[5]) + (pv[6] + pv[7]));
#pragma unroll
      for (int tt = 0; tt < 2; ++tt) {
        unsigned w0, w1;
        asm("v_cvt_pk_bf16_f32 %0, %1, %2"
            : "=v"(w0) : "v"(pv[tt * 4 + 0]), "v"(pv[tt * 4 + 1]));
        asm("v_cvt_pk_bf16_f32 %0, %1, %2"
            : "=v"(w1) : "v"(pv[tt * 4 + 2]), "v"(pv[tt * 4 + 3]));
        union { unsigned u[2]; bf16x4 v; } pk;
        pk.u[0] = w0; pk.u[1] = w1;
        pf[qf][tt] = pk.v;
      }
    }
  };

  auto pvstep = [&](const S8 (&vf)[4]) {
    __builtin_amdgcn_s_setprio(1);
#pragma unroll
    for (int qf = 0; qf < 2; ++qf)
#pragma unroll
      for (int tt = 0; tt < 2; ++tt)
#pragma unroll
        for (int dt = 0; dt < 4; ++dt)
          mfma16x16x16(accO[qf][dt], vf[dt].h[tt], pf[qf][tt]);
    __builtin_amdgcn_s_setprio(0);
  };

  // prologue: chunks 0,1,2 in flight (24 loads)
  ISSUE_K(k0); ISSUE_V(v0);
  ISSUE_K(k1); ISSUE_V(v1);
  ISSUE_K(k2); ISSUE_V(v2);

  // 21 iterations x 3 chunks = chunks 0..62; each chunk c issues c+3.
  // Issues for chunks 64,65 read past stream end into adjacent mapped ws
  // (harmless, drained by final WAITV(0), never consumed).
  for (int it = 0; it < 21; ++it) {
    WAITV(20); qksm(k0); WAITV(16); pvstep(v0); ISSUE_K(k0); ISSUE_V(v0);
    WAITV(20); qksm(k1); WAITV(16); pvstep(v1); ISSUE_K(k1); ISSUE_V(v1);
    WAITV(20); qksm(k2); WAITV(16); pvstep(v2); ISSUE_K(k2); ISSUE_V(v2);
  }
  // chunk 63 (buffer 0)
  WAITV(20); qksm(k0); WAITV(16); pvstep(v0);
  WAITV(0);  // drain dangling chunk-64/65 loads before epilogue / endpgm
#undef ISSUE_K
#undef ISSUE_V

  int b_ = bh >> 4, h_ = bh & 15;
#pragma unroll
  for (int qf = 0; qf < 2; ++qf) {
    float ls = lsum[qf];
    ls += __shfl_xor(ls, 16);
    ls += __shfl_xor(ls, 32);
    float inv = 1.f / ls;   // row q = l15: lane-local
    int sq = q0 + qf * 16 + l15;
#pragma unroll
    for (int dt = 0; dt < 4; ++dt)
#pragma unroll
      for (int r = 0; r < 4; ++r) {
        float val = accO[qf][dt][r] * inv;
        AO[(size_t)(b_ * SEQ + sq) * DM + h_ * DKH + dt * 16 + g * 4 + r] = f2bf(val);
      }
  }
}

extern "C" void kernel_launch(void* const* d_in, const int* in_sizes, int n_in,
                              void* d_out, int out_size, void* d_ws, size_t ws_size,
                              hipStream_t stream) {
  (void)in_sizes; (void)n_in; (void)out_size; (void)ws_size;
  const float* queries = (const float*)d_in[0];
  const float* keys = (const float*)d_in[1];
  const float* values = (const float*)d_in[2];
  const float* Wq = (const float*)d_in[3];
  const float* bq = (const float*)d_in[4];
  const float* Wk = (const float*)d_in[5];
  const float* bk = (const float*)d_in[6];
  const float* Wv = (const float*)d_in[7];
  const float* bv = (const float*)d_in[8];
  const float* Wo = (const float*)d_in[9];
  const float* bo = (const float*)d_in[10];
  float* out = (float*)d_out;

  char* ws = (char*)d_ws;
  unsigned short* wt_q = (unsigned short*)(ws + 0 * (1u << 21));
  unsigned short* wt_k = (unsigned short*)(ws + 1 * (1u << 21));
  unsigned short* wt_v = (unsigned short*)(ws + 2 * (1u << 21));
  unsigned short* wt_o = (unsigned short*)(ws + 3 * (1u << 21));
  unsigned short* Qb = (unsigned short*)(ws + (8u << 20));
  unsigned short* Kb = (unsigned short*)(ws + (24u << 20));
  unsigned short* Vt = (unsigned short*)(ws + (40u << 20));
  unsigned short* AO = (unsigned short*)(ws + (56u << 20));
  // total ws use: 72 MiB (AO doubles as the bf16-A ping-pong buffer)

  const float SQ = 0.125f * 1.4426950408889634f;  // fold 1/sqrt(64), log2(e) into Q

  wcast_all<<<dim3(32, 32, 4), 256, 0, stream>>>(Wq, Wk, Wv, Wo,
                                                 wt_q, wt_k, wt_v, wt_o);
  acast<<<4096, 256, 0, stream>>>(queries, AO);
  gemm_bf16<0><<<512, 256, 0, stream>>>(AO, wt_q, bq, Qb, SQ);
  acast<<<4096, 256, 0, stream>>>(keys, AO);
  gemm_bf16<1><<<512, 256, 0, stream>>>(AO, wt_k, bk, Kb, 1.0f);
  acast<<<4096, 256, 0, stream>>>(values, AO);
  gemm_bf16<2><<<512, 256, 0, stream>>>(AO, wt_v, bv, Vt, 1.0f);
  attn_fwd<<<4096, 64, 0, stream>>>(Qb, Kb, Vt, AO);
  gemm_bf16<3><<<512, 256, 0, stream>>>(AO, wt_o, bo, out, 1.0f);
}

// Round 22
// 232.292 us; speedup vs baseline: 1.0138x; 1.0138x over previous
//
#include <hip/hip_runtime.h>
#include <hip/hip_bf16.h>
#include <stdint.h>

#define DM 1024
#define DKH 64
#define NH 16
#define NB 4
#define SEQ 2048

typedef __attribute__((ext_vector_type(8))) short bf16x8;
typedef __attribute__((ext_vector_type(4))) short bf16x4;
typedef __attribute__((ext_vector_type(8))) unsigned short ushort8;
typedef __attribute__((ext_vector_type(4))) float f32x4;

union S8 { bf16x8 w; bf16x4 h[2]; };

__device__ inline unsigned short f2bf(float f) {
  union { float f; unsigned u; } c; c.f = f;
  unsigned u = c.u;
  u += 0x7fff + ((u >> 16) & 1);   // round-to-nearest-even
  return (unsigned short)(u >> 16);
}

// forced (un-sinkable) global loads with literal byte offsets
#define GLOAD16(dst, ptr, OFF)                                              \
  asm volatile("global_load_dwordx4 %0, %1, off offset:" #OFF               \
               : "=v"(dst) : "v"(ptr))

#define WAITV(N)                                            \
  do {                                                      \
    asm volatile("s_waitcnt vmcnt(" #N ")" ::: "memory");   \
    __builtin_amdgcn_sched_barrier(0);                      \
  } while (0)

// async global->LDS, 16B per lane; lds dest = wave-uniform base + lane*16
__device__ inline void glds16(const unsigned short* g, unsigned short* l) {
  __builtin_amdgcn_global_load_lds(
      (const __attribute__((address_space(1))) unsigned int*)g,
      (__attribute__((address_space(3))) unsigned int*)l, 16, 0, 0);
}

// PV matrix op: D/C = acc (4 VGPR), A = V-frag (4 bf16), B = P-frag (4 bf16)
__device__ inline void mfma16x16x16(f32x4& acc, bf16x4 a, bf16x4 b) {
  asm("v_mfma_f32_16x16x16_bf16 %0, %1, %2, %0" : "+v"(acc) : "v"(a), "v"(b));
}

// ---------- fp32 -> bf16 elementwise cast (8 elems/thread) ----------
__global__ __launch_bounds__(256) void acast(const float* __restrict__ A,
                                             unsigned short* __restrict__ O) {
  size_t i = ((size_t)blockIdx.x * 256 + threadIdx.x) * 8;
  const float* p = A + i;
  float4 x = *reinterpret_cast<const float4*>(p);
  float4 y = *reinterpret_cast<const float4*>(p + 4);
  ushort8 v;
  v[0] = f2bf(x.x); v[1] = f2bf(x.y); v[2] = f2bf(x.z); v[3] = f2bf(x.w);
  v[4] = f2bf(y.x); v[5] = f2bf(y.y); v[6] = f2bf(y.z); v[7] = f2bf(y.w);
  *reinterpret_cast<ushort8*>(O + i) = v;
}

// ---------- 4 weight transposes in one dispatch: Wt[n][k] = bf16(W[k][n]) ------
__global__ __launch_bounds__(256) void wcast_all(const float* __restrict__ W0,
                                                 const float* __restrict__ W1,
                                                 const float* __restrict__ W2,
                                                 const float* __restrict__ W3,
                                                 unsigned short* __restrict__ Wt0,
                                                 unsigned short* __restrict__ Wt1,
                                                 unsigned short* __restrict__ Wt2,
                                                 unsigned short* __restrict__ Wt3) {
  __shared__ float tile[32][33];
  int z = blockIdx.z;
  const float* W = z == 0 ? W0 : z == 1 ? W1 : z == 2 ? W2 : W3;
  unsigned short* Wt = z == 0 ? Wt0 : z == 1 ? Wt1 : z == 2 ? Wt2 : Wt3;
  int bk = blockIdx.x * 32, bn = blockIdx.y * 32;
  int tx = threadIdx.x & 31, ty = threadIdx.x >> 5;  // ty 0..7
#pragma unroll
  for (int i = 0; i < 4; ++i)
    tile[ty + 8 * i][tx] = W[(size_t)(bk + ty + 8 * i) * DM + bn + tx];
  __syncthreads();
#pragma unroll
  for (int i = 0; i < 4; ++i)
    Wt[(size_t)(bn + ty + 8 * i) * DM + bk + tx] = f2bf(tile[tx][ty + 8 * i]);
}

// ---------- bf16 GEMM: double-buffered LDS + counted vmcnt (T4) ----------
// M=8192, N=1024, K=1024, 128x128 tile, BK=32, 512 blocks.
// EPI: 0 = Q [B,H,S,64] bf16 (scaled); 1 = K' attn-native; 2 = V'' attn-native
//      packed; 3 = fp32 out row-major.
template <int EPI>
__global__ __launch_bounds__(256) void gemm_bf16(const unsigned short* __restrict__ A,
                                                 const unsigned short* __restrict__ Bt,
                                                 const float* __restrict__ bias,
                                                 void* __restrict__ Cv, float scale) {
  __shared__ __align__(16) unsigned short As[2][128][32];
  __shared__ __align__(16) unsigned short Bs[2][128][32];
  const int K = DM;
  int t = threadIdx.x;
  int wave = t >> 6, lane = t & 63;
  int wr = wave >> 1, wc = wave & 1;
  int l15 = lane & 15, g = lane >> 4;
  // XCD-locality swizzle (bijective on [0,512))
  int bid = blockIdx.x;
  int xcd = bid & 7, ii = bid >> 3;
  int tn = ii >> 3;                    // 0..7
  int tm = ((ii & 7) << 3) | xcd;      // 0..63
  int rowBase = tm * 128, colBase = tn * 128;

  f32x4 acc[4][4];
#pragma unroll
  for (int mi = 0; mi < 4; ++mi)
#pragma unroll
    for (int ni = 0; ni < 4; ++ni) acc[mi][ni] = (f32x4){0.f, 0.f, 0.f, 0.f};

  const unsigned short* sa0 =
      A + (size_t)(rowBase + wave * 16 + (lane >> 2)) * K + (lane & 3) * 8;
  const unsigned short* sa1 = sa0 + (size_t)64 * K;
  const unsigned short* sb0 =
      Bt + (size_t)(colBase + wave * 16 + (lane >> 2)) * K + (lane & 3) * 8;
  const unsigned short* sb1 = sb0 + (size_t)64 * K;

#define STAGE(BUF)                                   \
  do {                                               \
    glds16(sa0, &As[BUF][wave * 16][0]);             \
    glds16(sa1, &As[BUF][64 + wave * 16][0]);        \
    glds16(sb0, &Bs[BUF][wave * 16][0]);             \
    glds16(sb1, &Bs[BUF][64 + wave * 16][0]);        \
    sa0 += 32; sa1 += 32; sb0 += 32; sb1 += 32;      \
  } while (0)

#define COMPUTE(BUF)                                                            \
  do {                                                                          \
    bf16x8 af[4], bfr[4];                                                       \
    _Pragma("unroll")                                                           \
    for (int mi = 0; mi < 4; ++mi)                                              \
      af[mi] = *reinterpret_cast<const bf16x8*>(                                \
          &As[BUF][wr * 64 + mi * 16 + l15][g * 8]);                            \
    _Pragma("unroll")                                                           \
    for (int ni = 0; ni < 4; ++ni)                                              \
      bfr[ni] = *reinterpret_cast<const bf16x8*>(                               \
          &Bs[BUF][wc * 64 + ni * 16 + l15][g * 8]);                            \
    _Pragma("unroll")                                                           \
    for (int mi = 0; mi < 4; ++mi)                                              \
      _Pragma("unroll")                                                         \
      for (int ni = 0; ni < 4; ++ni)                                            \
        acc[mi][ni] = __builtin_amdgcn_mfma_f32_16x16x32_bf16(af[mi], bfr[ni],  \
                                                              acc[mi][ni], 0, 0, 0); \
  } while (0)

  STAGE(0);  // tile 0 in flight (4 DMAs)
#pragma unroll 1
  for (int it = 0; it < 16; ++it) {   // each iteration: tiles 2it, 2it+1
    __syncthreads();                  // all waves done reading buf1 (prev iter)
    STAGE(1);                         // tile 2it+1 -> buf1
    WAITV(4);                         // my buf0 DMAs (tile 2it) complete
    __syncthreads();                  // everyone's buf0 complete
    COMPUTE(0);
    __syncthreads();                  // all waves done reading buf0
    if (it < 15) {
      STAGE(0);                       // tile 2it+2 -> buf0
      WAITV(4);                       // buf1 (tile 2it+1) complete
    } else {
      WAITV(0);                       // final drain
    }
    __syncthreads();
    COMPUTE(1);
  }
#undef STAGE
#undef COMPUTE

#pragma unroll
  for (int ni = 0; ni < 4; ++ni) {
    int col = colBase + wc * 64 + ni * 16 + l15;
    float bvv = bias[col];
#pragma unroll
    for (int mi = 0; mi < 4; ++mi) {
#pragma unroll
      for (int r = 0; r < 4; ++r) {
        int row = rowBase + wr * 64 + mi * 16 + g * 4 + r;
        float val = (acc[mi][ni][r] + bvv) * scale;
        if (EPI == 3) {
          ((float*)Cv)[(size_t)row * DM + col] = val;
        } else {
          int b_ = row >> 11, s_ = row & 2047;
          int h_ = col >> 6, d_ = col & 63;
          size_t hb = (size_t)(b_ * NH + h_) * (SEQ * DKH);
          size_t idx;
          if (EPI == 0) {
            idx = hb + (size_t)s_ * DKH + d_;
          } else if (EPI == 1) {
            idx = hb + (size_t)(s_ >> 4) * 1024 + (d_ >> 5) * 512 +
                  ((d_ >> 3) & 3) * 128 + (s_ & 15) * 8 + (d_ & 7);
          } else {
            // V'' packed: lane(g,l15) reads 16B = {tt=0 j0..3, tt=1 j0..3}
            idx = hb + (size_t)(s_ >> 5) * 2048 + (d_ >> 4) * 512 +
                  ((s_ >> 2) & 3) * 128 + (d_ & 15) * 8 + ((s_ >> 4) & 1) * 4 +
                  (s_ & 3);
          }
          ((unsigned short*)Cv)[idx] = f2bf(val);
        }
      }
    }
  }
}

// ---------- flash attention: zero-LDS, fixed-offset softmax (best: r13/r18) ----
// P = 2^(s-16) with the offset folded into the QK MFMA C-init (zero VALU).
// K': 4x GLOAD16/chunk; V'': 4x GLOAD16/chunk (packed). 3-buffer rotation,
// prefetch distance 2; counted vmcnt 20/16 (never 0 mid-loop). T5 setprio.
__global__ __launch_bounds__(256) void attn_fwd(const unsigned short* __restrict__ Qb,
                                                const unsigned short* __restrict__ Kp_,
                                                const unsigned short* __restrict__ Vp_,
                                                unsigned short* __restrict__ AO) {
  int t = threadIdx.x;
  int wave = t >> 6, lane = t & 63;
  int l15 = lane & 15, g = lane >> 4;
  int bid = blockIdx.x;                 // 0..1023
  int xcd = bid & 7, j = bid >> 3;      // j 0..127
  int bh = (xcd << 3) | (j >> 4);       // 0..63
  int qtile = j & 15;                   // 0..15
  const size_t baseH = (size_t)bh * SEQ * DKH;
  int q0 = qtile * 128 + wave * 32;

  bf16x8 aQ[2][2];
#pragma unroll
  for (int qf = 0; qf < 2; ++qf)
#pragma unroll
    for (int dh = 0; dh < 2; ++dh)
      aQ[qf][dh] = *reinterpret_cast<const bf16x8*>(
          Qb + baseH + (size_t)(q0 + qf * 16 + l15) * DKH + dh * 32 + g * 8);

  float lsum[2] = {0.f, 0.f};
  f32x4 accO[2][4];  // accO[qf][dt][r] = O[q=l15][d=dt*16+g*4+r]
#pragma unroll
  for (int qf = 0; qf < 2; ++qf)
#pragma unroll
    for (int dt = 0; dt < 4; ++dt) accO[qf][dt] = (f32x4){0.f, 0.f, 0.f, 0.f};

  const unsigned short* kp = Kp_ + baseH + g * 128 + l15 * 8;
  const unsigned short* vp = Vp_ + baseH + (size_t)lane * 8;  // lane*16B

  bf16x8 k0[2][2], k1[2][2], k2[2][2];
  S8 v0[4], v1[4], v2[4];
  bf16x4 pf[2][2];

#define ISSUE_K(buf)                                  \
  do {                                                \
    GLOAD16(buf[0][0], kp, 0);                        \
    GLOAD16(buf[0][1], kp, 1024);                     \
    GLOAD16(buf[1][0], kp, 2048);                     \
    GLOAD16(buf[1][1], kp, 3072);                     \
    kp += 2048;                                       \
  } while (0)
#define ISSUE_V(buf)                                  \
  do {                                                \
    GLOAD16(buf[0].w, vp, 0);                         \
    GLOAD16(buf[1].w, vp, 1024);                      \
    GLOAD16(buf[2].w, vp, 2048);                      \
    GLOAD16(buf[3].w, vp, 3072);                      \
    vp += 2048;                                       \
  } while (0)

  const f32x4 ZOFF = (f32x4){-16.f, -16.f, -16.f, -16.f};

  auto qksm = [&](const bf16x8 (&kf)[2][2]) {
    f32x4 sc[2][2];
    __builtin_amdgcn_s_setprio(1);
#pragma unroll
    for (int qf = 0; qf < 2; ++qf)
#pragma unroll
      for (int tt = 0; tt < 2; ++tt) {
        f32x4 z = ZOFF;  // C-init = -16: folds the softmax offset for free
#pragma unroll
        for (int dh = 0; dh < 2; ++dh)
          z = __builtin_amdgcn_mfma_f32_16x16x32_bf16(kf[tt][dh], aQ[qf][dh], z, 0, 0, 0);
        sc[qf][tt] = z;
      }
    __builtin_amdgcn_s_setprio(0);
#pragma unroll
    for (int qf = 0; qf < 2; ++qf) {
      float pv[8];
#pragma unroll
      for (int tt = 0; tt < 2; ++tt)
#pragma unroll
        for (int r = 0; r < 4; ++r)
          pv[tt * 4 + r] = __builtin_amdgcn_exp2f(sc[qf][tt][r]);
      lsum[qf] +=
          ((pv[0] + pv[1]) + (pv[2] + pv[3])) + ((pv[4] + pv[5]) + (pv[6] + pv[7]));
#pragma unroll
      for (int tt = 0; tt < 2; ++tt) {
        unsigned w0, w1;
        asm("v_cvt_pk_bf16_f32 %0, %1, %2"
            : "=v"(w0) : "v"(pv[tt * 4 + 0]), "v"(pv[tt * 4 + 1]));
        asm("v_cvt_pk_bf16_f32 %0, %1, %2"
            : "=v"(w1) : "v"(pv[tt * 4 + 2]), "v"(pv[tt * 4 + 3]));
        union { unsigned u[2]; bf16x4 v; } pk;
        pk.u[0] = w0; pk.u[1] = w1;
        pf[qf][tt] = pk.v;
      }
    }
  };

  auto pvstep = [&](const S8 (&vf)[4]) {
    __builtin_amdgcn_s_setprio(1);
#pragma unroll
    for (int qf = 0; qf < 2; ++qf)
#pragma unroll
      for (int tt = 0; tt < 2; ++tt)
#pragma unroll
        for (int dt = 0; dt < 4; ++dt)
          mfma16x16x16(accO[qf][dt], vf[dt].h[tt], pf[qf][tt]);
    __builtin_amdgcn_s_setprio(0);
  };

  // prologue: chunks 0,1,2 in flight (24 loads)
  ISSUE_K(k0); ISSUE_V(v0);
  ISSUE_K(k1); ISSUE_V(v1);
  ISSUE_K(k2); ISSUE_V(v2);

  // 21 iterations x 3 chunks = chunks 0..62; each chunk c issues c+3.
  // Issues for chunks 64,65 read past stream end into adjacent mapped ws
  // (harmless, drained by final WAITV(0), never consumed).
  for (int it = 0; it < 21; ++it) {
    WAITV(20); qksm(k0); WAITV(16); pvstep(v0); ISSUE_K(k0); ISSUE_V(v0);
    WAITV(20); qksm(k1); WAITV(16); pvstep(v1); ISSUE_K(k1); ISSUE_V(v1);
    WAITV(20); qksm(k2); WAITV(16); pvstep(v2); ISSUE_K(k2); ISSUE_V(v2);
  }
  // chunk 63 (buffer 0)
  WAITV(20); qksm(k0); WAITV(16); pvstep(v0);
  WAITV(0);  // drain dangling chunk-64/65 loads before epilogue / endpgm
#undef ISSUE_K
#undef ISSUE_V

  int b_ = bh >> 4, h_ = bh & 15;
#pragma unroll
  for (int qf = 0; qf < 2; ++qf) {
    float ls = lsum[qf];
    ls += __shfl_xor(ls, 16);
    ls += __shfl_xor(ls, 32);
    float inv = 1.f / ls;   // row q = l15: lane-local
    int sq = q0 + qf * 16 + l15;
#pragma unroll
    for (int dt = 0; dt < 4; ++dt)
#pragma unroll
      for (int r = 0; r < 4; ++r) {
        float val = accO[qf][dt][r] * inv;
        AO[(size_t)(b_ * SEQ + sq) * DM + h_ * DKH + dt * 16 + g * 4 + r] = f2bf(val);
      }
  }
}

extern "C" void kernel_launch(void* const* d_in, const int* in_sizes, int n_in,
                              void* d_out, int out_size, void* d_ws, size_t ws_size,
                              hipStream_t stream) {
  (void)in_sizes; (void)n_in; (void)out_size; (void)ws_size;
  const float* queries = (const float*)d_in[0];
  const float* keys = (const float*)d_in[1];
  const float* values = (const float*)d_in[2];
  const float* Wq = (const float*)d_in[3];
  const float* bq = (const float*)d_in[4];
  const float* Wk = (const float*)d_in[5];
  const float* bk = (const float*)d_in[6];
  const float* Wv = (const float*)d_in[7];
  const float* bv = (const float*)d_in[8];
  const float* Wo = (const float*)d_in[9];
  const float* bo = (const float*)d_in[10];
  float* out = (float*)d_out;

  char* ws = (char*)d_ws;
  unsigned short* wt_q = (unsigned short*)(ws + 0 * (1u << 21));
  unsigned short* wt_k = (unsigned short*)(ws + 1 * (1u << 21));
  unsigned short* wt_v = (unsigned short*)(ws + 2 * (1u << 21));
  unsigned short* wt_o = (unsigned short*)(ws + 3 * (1u << 21));
  unsigned short* Qb = (unsigned short*)(ws + (8u << 20));
  unsigned short* Kb = (unsigned short*)(ws + (24u << 20));
  unsigned short* Vt = (unsigned short*)(ws + (40u << 20));
  unsigned short* AO = (unsigned short*)(ws + (56u << 20));
  // total ws use: 72 MiB (AO doubles as the bf16-A ping-pong buffer)

  const float SQ = 0.125f * 1.4426950408889634f;  // fold 1/sqrt(64), log2(e) into Q

  wcast_all<<<dim3(32, 32, 4), 256, 0, stream>>>(Wq, Wk, Wv, Wo,
                                                 wt_q, wt_k, wt_v, wt_o);
  acast<<<4096, 256, 0, stream>>>(queries, AO);
  gemm_bf16<0><<<512, 256, 0, stream>>>(AO, wt_q, bq, Qb, SQ);
  acast<<<4096, 256, 0, stream>>>(keys, AO);
  gemm_bf16<1><<<512, 256, 0, stream>>>(AO, wt_k, bk, Kb, 1.0f);
  acast<<<4096, 256, 0, stream>>>(values, AO);
  gemm_bf16<2><<<512, 256, 0, stream>>>(AO, wt_v, bv, Vt, 1.0f);
  attn_fwd<<<1024, 256, 0, stream>>>(Qb, Kb, Vt, AO);
  gemm_bf16<3><<<512, 256, 0, stream>>>(AO, wt_o, bo, out, 1.0f);
}